// Round 5
// baseline (2042.466 us; speedup 1.0000x reference)
//
#include <hip/hip_runtime.h>
#include <stdint.h>

typedef unsigned char u8;
typedef unsigned short u16;
typedef uint32_t u32;

#define NTOT 4096
#define SS   32
#define DD   128
#define EPSK 1e-6f
#define NITER 20
#define CAPC 4460544u      // max nt*roundup(nc,128) over all splits with nt,nc<=2304
#define LDC_FIT 2304       // LDS-resident z/w limit (nt,nc=2048±8sigma safe)
#define WSTR 2432          // per-ts vector stride (floats)
#define SU_OFF 2308
#define UNT_OFF 2309
#define BPT 24             // blocks per timestep in iteration kernels (24*32=768=3/CU)

typedef __attribute__((ext_vector_type(8))) short short8;
typedef __attribute__((ext_vector_type(4))) float f32x4;
typedef __attribute__((ext_vector_type(2))) float f32x2;

__device__ __forceinline__ float bf2f(u16 h){ return __uint_as_float(((u32)h) << 16); }
__device__ __forceinline__ u16 f2bf(float f){
  u32 u = __float_as_uint(f);
  u += 0x7fffu + ((u >> 16) & 1u);
  return (u16)(u >> 16);
}
// column permutation within each 64-col group: col j*16+r  <->  stored r*4+j
__device__ __forceinline__ int invpermc(int cp){
  return (cp & ~63) | ((cp & 3) << 4) | ((cp >> 2) & 15);
}
// decode 16 packed fp8 bytes -> 16 floats (HW cvt)
__device__ __forceinline__ void dec16(uint4 kq, float* kd){
  u32 wd[4] = {kq.x, kq.y, kq.z, kq.w};
  #pragma unroll
  for (int q = 0; q < 4; q++){
    f32x2 d0 = __builtin_amdgcn_cvt_pk_f32_fp8((int)wd[q], false);
    f32x2 d1 = __builtin_amdgcn_cvt_pk_f32_fp8((int)wd[q], true);
    kd[q*4+0] = d0.x; kd[q*4+1] = d0.y; kd[q*4+2] = d1.x; kd[q*4+3] = d1.y;
  }
}

// ---------------- compact treated/control index lists --------------------------------
__global__ __launch_bounds__(1024) void k_compact(const int* __restrict__ t,
    int* __restrict__ itidx, int* __restrict__ icidx, int* __restrict__ meta,
    float* __restrict__ fmeta)
{
  __shared__ int sc[1024];
  int tid = threadIdx.x;
  int e0 = tid * 4;
  int tv[4]; int c = 0;
  #pragma unroll
  for (int e = 0; e < 4; e++){ tv[e] = t[e0 + e]; c += (tv[e] > 0) ? 1 : 0; }
  sc[tid] = c;
  __syncthreads();
  for (int off = 1; off < 1024; off <<= 1){
    int v = sc[tid];
    int add = (tid >= off) ? sc[tid - off] : 0;
    __syncthreads();
    sc[tid] = v + add;
    __syncthreads();
  }
  int incl = sc[tid];
  int excl = incl - c;
  int oT = excl, oC = e0 - excl;
  #pragma unroll
  for (int e = 0; e < 4; e++){
    if (tv[e] > 0) itidx[oT++] = e0 + e;
    else           icidx[oC++] = e0 + e;
  }
  if (tid == 1023){
    meta[0] = incl; meta[1] = NTOT - incl;
    fmeta[0] = (float)incl / (float)NTOT;
  }
}

__global__ void k_zero(float* __restrict__ p, int n)
{
  int i = blockIdx.x * 256 + threadIdx.x;
  if (i < n) p[i] = 0.f;
}

// ---------------- init w-slot-0 scalars -----------------------------------------------
__global__ void k_vinit(const float* __restrict__ fmeta, float* __restrict__ w0)
{
  if (threadIdx.x == 0){
    float p = fmeta[0];
    float* w = w0 + (size_t)blockIdx.x * WSTR;
    w[SU_OFF]  = p;
    w[UNT_OFF] = 1.0f - p;
  }
}

// ---------------- gather X -> bf16 Xt/Xc + row norms ----------------------------------
__global__ __launch_bounds__(256) void k_pack(const float* __restrict__ X,
    const int* __restrict__ itidx, const int* __restrict__ icidx,
    const int* __restrict__ meta, u16* __restrict__ XT, u16* __restrict__ XC,
    float* __restrict__ nxT, float* __restrict__ nxC, int ts0)
{
  int r = blockIdx.x * 256 + threadIdx.x;
  int isC = blockIdx.y;
  int z = blockIdx.z;
  int s = ts0 + z;
  int n = isC ? meta[1] : meta[0];
  if (r >= n) return;
  int idx = isC ? icidx[r] : itidx[r];
  const float4* src = (const float4*)(X + ((size_t)idx * SS + s) * DD);
  u16* dst = (isC ? XC : XT) + ((size_t)z * NTOT + r) * DD;
  float nrm = 0.f;
  #pragma unroll
  for (int q = 0; q < 32; q++){
    float4 v = src[q];
    nrm += v.x*v.x + v.y*v.y + v.z*v.z + v.w*v.w;
    u32 lo = (u32)f2bf(v.x) | ((u32)f2bf(v.y) << 16);
    u32 hi = (u32)f2bf(v.z) | ((u32)f2bf(v.w) << 16);
    uint2 pk; pk.x = lo; pk.y = hi;
    ((uint2*)dst)[q] = pk;
  }
  (isC ? nxC : nxT)[z * NTOT + r] = nrm;
}

// ---------------- per-ts column sums + norm sums (for analytic mean(M)) ---------------
__global__ __launch_bounds__(256) void k_stats(const u16* __restrict__ XT,
    const u16* __restrict__ XC, const float* __restrict__ nxT, const float* __restrict__ nxC,
    const int* __restrict__ meta, float* __restrict__ gsx, float* __restrict__ gsn)
{
  int side = blockIdx.y, z = blockIdx.z;
  int n = side ? meta[1] : meta[0];
  int chunk = (n + 7) >> 3;
  int r0 = blockIdx.x * chunk;
  int r1 = min(r0 + chunk, n);
  const u16* B = (side ? XC : XT) + (size_t)z * NTOT * DD;
  int tid = threadIdx.x;
  int d = tid & 127, half = tid >> 7;
  float sx = 0.f;
  for (int r = r0 + half; r < r1; r += 2) sx += bf2f(B[(size_t)r * DD + d]);
  __shared__ float sp[256];
  sp[tid] = sx;
  __syncthreads();
  if (tid < 128) unsafeAtomicAdd(&gsx[(size_t)(z*2+side)*128 + tid], sp[tid] + sp[tid+128]);
  const float* nrm = (side ? nxC : nxT) + (size_t)z * NTOT;
  float sn = 0.f;
  for (int r = r0 + tid; r < r1; r += 256) sn += nrm[r];
  #pragma unroll
  for (int o = 32; o; o >>= 1) sn += __shfl_xor(sn, o);
  __syncthreads();
  if ((tid & 63) == 0) sp[tid >> 6] = sn;
  __syncthreads();
  if (tid == 0) unsafeAtomicAdd(&gsn[z*2+side], sp[0]+sp[1]+sp[2]+sp[3]);
}

// ---------------- lam = nt*nc/sum(M) analytically --------------------------------------
__global__ void k_lam(const float* __restrict__ gsx, const float* __restrict__ gsn,
                      const int* __restrict__ meta, float* __restrict__ stats)
{
  int z = blockIdx.x, tid = threadIdx.x;  // 128 threads
  float d = gsx[(size_t)(z*2)*128 + tid] * gsx[(size_t)(z*2+1)*128 + tid];
  #pragma unroll
  for (int o = 32; o; o >>= 1) d += __shfl_xor(d, o);
  __shared__ float rr[2];
  if ((tid & 63) == 0) rr[tid >> 6] = d;
  __syncthreads();
  if (tid == 0){
    float nt = (float)meta[0], nc = (float)meta[1];
    float msum = nc * gsn[z*2] + nt * gsn[z*2+1] - 2.f * (rr[0] + rr[1]);
    stats[z*8+0] = nt * nc / msum;   // lam
    stats[z*8+1] = msum / (nt * nc); // 1/lam = mean(M)
  }
}

// ---------------- GEMM: K = fp8(exp(-lam*M)) (HW cvt, permuted direct store) ----------
#define LDA2 72
__global__ __launch_bounds__(256, 4) void k_gemm(const u16* __restrict__ XT,
    const u16* __restrict__ XC, const float* __restrict__ nxT, const float* __restrict__ nxC,
    const int* __restrict__ meta, const float* __restrict__ fmeta,
    float* __restrict__ stats, u8* __restrict__ Kc, float* __restrict__ w0base)
{
  int nt = meta[0], nc = meta[1];
  if (nt > LDC_FIT || nc > LDC_FIT) return;
  int bx = blockIdx.x, by = blockIdx.y, z = blockIdx.z;
  if (by * 128 >= nt || bx * 128 >= nc) return;
  __shared__ __align__(16) u16 As[128 * LDA2];
  __shared__ __align__(16) u16 Bs[128 * LDA2];
  __shared__ float watile[256];
  __shared__ float nxs[128];
  __shared__ float nys[128];
  int tid = threadIdx.x;
  int wid = tid >> 6, lane = tid & 63;
  int wm = (wid >> 1) * 64, wn = (wid & 1) * 64;
  int lrow = lane & 15, lquad = lane >> 4;

  // stage this block's row/col norms into LDS (coalesced, once)
  if (tid < 128){
    int gi = by*128 + tid;
    nxs[tid] = (gi < nt) ? nxT[(size_t)z * NTOT + gi] : 0.f;
  } else {
    int gj = bx*128 + (tid - 128);
    nys[tid - 128] = (gj < nc) ? nxC[(size_t)z * NTOT + gj] : 0.f;
  }

  f32x4 acc[4][4];
  #pragma unroll
  for (int i = 0; i < 4; i++){
    #pragma unroll
    for (int j = 0; j < 4; j++){
      acc[i][j][0]=0.f; acc[i][j][1]=0.f; acc[i][j][2]=0.f; acc[i][j][3]=0.f;
    }
  }

  int r = tid & 127;
  int isB = tid >> 7;
  int g = (isB ? bx : by) * 128 + r;
  int lim = isB ? nc : nt;
  const u16* srcbase = (isB ? XC : XT) + ((size_t)z * NTOT + g) * DD;
  u16* dl = (isB ? Bs : As) + r * LDA2;

  for (int kh = 0; kh < 2; kh++){
    __syncthreads();
    if (g < lim){
      const uint4* src = (const uint4*)(srcbase + kh * 64);
      #pragma unroll
      for (int q = 0; q < 8; q++) ((uint4*)dl)[q] = src[q];
    } else {
      uint4 zz; zz.x=0; zz.y=0; zz.z=0; zz.w=0;
      #pragma unroll
      for (int q = 0; q < 8; q++) ((uint4*)dl)[q] = zz;
    }
    __syncthreads();
    #pragma unroll
    for (int ks = 0; ks < 2; ks++){
      int koff = ks * 32 + lquad * 8;
      short8 af[4], bfr[4];
      #pragma unroll
      for (int i = 0; i < 4; i++) af[i]  = *(const short8*)(As + (wm + i*16 + lrow) * LDA2 + koff);
      #pragma unroll
      for (int j = 0; j < 4; j++) bfr[j] = *(const short8*)(Bs + (wn + j*16 + lrow) * LDA2 + koff);
      #pragma unroll
      for (int i = 0; i < 4; i++){
        #pragma unroll
        for (int j = 0; j < 4; j++){
          acc[i][j] = __builtin_amdgcn_mfma_f32_16x16x32_bf16(af[i], bfr[j], acc[i][j], 0, 0, 0);
        }
      }
    }
  }

  // ---- epilogue: exp -> HW fp8 pack -> permuted coalesced u32 stores ----
  int ldc = (nc + 127) & ~127;
  float lam = stats[z*8+0];
  float p = fmeta[0];
  float a0 = p / (float)nt;
  u8* Kz = Kc + (size_t)z * CAPC;

  float nyv[4]; bool jin[4];
  #pragma unroll
  for (int j = 0; j < 4; j++){
    int lcol = wn + j*16 + lrow;
    jin[j] = (bx*128 + lcol) < nc;
    nyv[j] = nys[lcol];
  }
  float vmax = 0.f;
  float colsum[4] = {0.f, 0.f, 0.f, 0.f};
  size_t cbase = (size_t)(bx*128 + wn + lrow*4);
  #pragma unroll
  for (int i = 0; i < 4; i++){
    #pragma unroll
    for (int rr2 = 0; rr2 < 4; rr2++){
      int lr = wm + i*16 + lquad*4 + rr2;
      int gi = by*128 + lr;
      bool iin = gi < nt;
      float nxv = nxs[lr];
      float cv[4];
      #pragma unroll
      for (int j = 0; j < 4; j++){
        float m = nxv + nyv[j] - 2.0f * acc[i][j][rr2];
        cv[j] = __expf(-lam * m);
        if (iin && jin[j]){ vmax = fmaxf(vmax, m); colsum[j] += cv[j]; }
      }
      u32 pk = (u32)__builtin_amdgcn_cvt_pk_fp8_f32(cv[0], cv[1], 0, false);
      pk = (u32)__builtin_amdgcn_cvt_pk_fp8_f32(cv[2], cv[3], (int)pk, true);
      if (iin) *(u32*)(Kz + (size_t)gi * ldc + cbase) = pk;
    }
  }
  // merge colsum over the 4 quads of this wave
  #pragma unroll
  for (int j = 0; j < 4; j++){
    colsum[j] += __shfl_xor(colsum[j], 16);
    colsum[j] += __shfl_xor(colsum[j], 32);
  }
  if (lane < 16){
    #pragma unroll
    for (int j = 0; j < 4; j++) watile[wid * 64 + j*16 + lrow] = colsum[j];
  }
  #pragma unroll
  for (int o = 32; o; o >>= 1) vmax = fmaxf(vmax, __shfl_xor(vmax, o));
  if (lane == 0) atomicMax((int*)stats + z*8 + 2, __float_as_int(vmax));
  __syncthreads();
  // w0 = (p/nt) * column sums
  if (tid < 128){
    int gj = bx*128 + tid;
    if (gj < nc){
      float v = (tid < 64) ? (watile[tid] + watile[128 + tid])
                           : (watile[64 + (tid-64)] + watile[192 + (tid-64)]);
      unsafeAtomicAdd(w0base + (size_t)z * WSTR + gj, v * a0);
    }
  }
}

// ---------------- fused Sinkhorn iteration: z(w) -> u' -> w' = K^T u' ------------------
__global__ __launch_bounds__(256, 3) void k_iter(const u8* __restrict__ Kc,
    const float* __restrict__ wprev, float* __restrict__ wnext,
    float* __restrict__ ubuf, const int* __restrict__ meta,
    const float* __restrict__ fmeta, const float* __restrict__ stats, int writeU)
{
  __shared__ __align__(16) float zl[LDC_FIT];
  __shared__ float watw[LDC_FIT];
  __shared__ float red[4];
  int nt = meta[0], nc = meta[1];
  if (nt > LDC_FIT || nc > LDC_FIT) return;
  int ldc = (nc + 127) & ~127;
  int z = blockIdx.y, b = blockIdx.x;
  int tid = threadIdx.x, wid = tid >> 6, lane = tid & 63;
  float p = fmeta[0];
  float b0 = (1.0f - p) / (float)nc;
  float a0 = p / (float)nt;
  float lam = stats[z*8+0];
  float delta = stats[z*8+2];
  float kc = __expf(-lam * delta);
  float kce = kc + EPSK;
  const float* wp = wprev + (size_t)z * WSTR;
  float* wnx = wnext + (size_t)z * WSTR;
  float SU = wp[SU_OFF], UNT = wp[UNT_OFF];
  float wext = EPSK * (SU + UNT) + kc * UNT;
  float wnc = kce * SU + (1.0f + EPSK) * UNT;
  float znc = p / wnc;

  // stage z into LDS in PERMUTED order; zero the shared w' accumulator
  float zp = 0.f;
  for (int cp = tid; cp < ldc; cp += 256){
    int c = invpermc(cp);
    float v = 0.f;
    if (c < nc) v = b0 * __builtin_amdgcn_rcpf(wp[c] + wext);
    zl[cp] = v;
    watw[cp] = 0.f;
    zp += v;
  }
  #pragma unroll
  for (int o = 32; o; o >>= 1) zp += __shfl_xor(zp, o);
  if (lane == 0) red[wid] = zp;
  __syncthreads();
  float Z = red[0] + red[1] + red[2] + red[3];
  float dotX = EPSK * Z + kce * znc;
  float untN = (1.0f - p) / (kce * Z + (1.0f + EPSK) * znc);

  // hoist this lane's z values into registers
  int cb0 = lane * 16;
  float zv[48];
  #pragma unroll
  for (int s = 0; s < 3; s++){
    int cb = s*1024 + cb0;
    if (cb < ldc){
      #pragma unroll
      for (int q = 0; q < 4; q++){
        float4 t4 = *(const float4*)(zl + cb + q*4);
        zv[s*16+q*4+0]=t4.x; zv[s*16+q*4+1]=t4.y; zv[s*16+q*4+2]=t4.z; zv[s*16+q*4+3]=t4.w;
      }
    } else {
      #pragma unroll
      for (int k = 0; k < 16; k++) zv[s*16+k] = 0.f;
    }
  }

  float wacc[48];
  #pragma unroll
  for (int k = 0; k < 48; k++) wacc[k] = 0.f;
  float rsum = 0.f;

  int rpb = (nt + BPT - 1) / BPT;
  int r0 = b * rpb, r1 = min(r0 + rpb, nt);
  const u8* Kz = Kc + (size_t)z * CAPC;
  uint4 zq; zq.x=0u; zq.y=0u; zq.z=0u; zq.w=0u;

  // software-pipelined row loop: prefetch next row while computing current
  int r = r0 + wid;
  uint4 cur[3] = {zq, zq, zq};
  if (r < r1){
    const u8* Kr = Kz + (size_t)r * ldc;
    cur[0] = *(const uint4*)(Kr + cb0);
    if (1024 + cb0 < ldc) cur[1] = *(const uint4*)(Kr + 1024 + cb0);
    if (2048 + cb0 < ldc) cur[2] = *(const uint4*)(Kr + 2048 + cb0);
  }
  while (r < r1){
    int rn = r + 4;
    uint4 nxt[3] = {zq, zq, zq};
    if (rn < r1){
      const u8* Krn = Kz + (size_t)rn * ldc;
      nxt[0] = *(const uint4*)(Krn + cb0);
      if (1024 + cb0 < ldc) nxt[1] = *(const uint4*)(Krn + 1024 + cb0);
      if (2048 + cb0 < ldc) nxt[2] = *(const uint4*)(Krn + 2048 + cb0);
    }
    // phase 1: decode + 4-chain dot
    float d4[4] = {0.f, 0.f, 0.f, 0.f};
    #pragma unroll
    for (int s = 0; s < 3; s++){
      float kd[16];
      dec16(cur[s], kd);
      #pragma unroll
      for (int k = 0; k < 16; k++) d4[k & 3] = fmaf(kd[k], zv[s*16+k], d4[k & 3]);
    }
    float dot = (d4[0] + d4[1]) + (d4[2] + d4[3]);
    #pragma unroll
    for (int o = 32; o; o >>= 1) dot += __shfl_xor(dot, o);
    float uv = a0 * __builtin_amdgcn_rcpf(dot + dotX);
    rsum += uv;
    if (writeU && lane == 0) ubuf[(size_t)z * WSTR + r] = uv;
    // phase 2: re-decode + accumulate w' partials
    #pragma unroll
    for (int s = 0; s < 3; s++){
      float kd[16];
      dec16(cur[s], kd);
      #pragma unroll
      for (int k = 0; k < 16; k++) wacc[s*16+k] = fmaf(kd[k], uv, wacc[s*16+k]);
    }
    cur[0] = nxt[0]; cur[1] = nxt[1]; cur[2] = nxt[2];
    r = rn;
  }
  // flush per-lane partials into the shared accumulator (LDS atomics; addresses
  // are distinct within a wave, 4-way across waves)
  #pragma unroll
  for (int s = 0; s < 3; s++){
    int cb = s*1024 + cb0;
    if (cb < ldc){
      #pragma unroll
      for (int k = 0; k < 16; k++) atomicAdd(&watw[cb + k], wacc[s*16+k]);
    }
  }
  if (lane == 0) unsafeAtomicAdd(wnx + SU_OFF, rsum);
  if (b == 0 && tid == 0) wnx[UNT_OFF] = untN;
  __syncthreads();
  for (int cp = tid; cp < ldc; cp += 256){
    int c = invpermc(cp);
    if (c < nc) unsafeAtomicAdd(wnx + c, watw[cp]);
  }
}

// ---------------- final: tsacc += sum(T * Mt), M recovered via -log(K)/lam -------------
__global__ __launch_bounds__(256, 3) void k_fin(const u8* __restrict__ Kc,
    const float* __restrict__ wprev, const float* __restrict__ ubuf,
    const int* __restrict__ meta, const float* __restrict__ fmeta,
    const float* __restrict__ stats, float* __restrict__ tsacc, int ts0)
{
  __shared__ __align__(16) float zl[LDC_FIT];
  __shared__ float red[4];
  int nt = meta[0], nc = meta[1];
  if (nt > LDC_FIT || nc > LDC_FIT) return;
  int ldc = (nc + 127) & ~127;
  int z = blockIdx.y, b = blockIdx.x;
  int tid = threadIdx.x, wid = tid >> 6, lane = tid & 63;
  float p = fmeta[0];
  float b0 = (1.0f - p) / (float)nc;
  float lam = stats[z*8+0];
  float invlam = stats[z*8+1];
  float delta = stats[z*8+2];
  float kc = __expf(-lam * delta);
  float kce = kc + EPSK;
  const float* wp = wprev + (size_t)z * WSTR;
  float SU = wp[SU_OFF], UNT = wp[UNT_OFF];
  float wext = EPSK * (SU + UNT) + kc * UNT;
  float wnc = kce * SU + (1.0f + EPSK) * UNT;
  float znc = p / wnc;

  float zp = 0.f;
  for (int cp = tid; cp < ldc; cp += 256){
    int c = invpermc(cp);
    float v = 0.f;
    if (c < nc) v = b0 * __builtin_amdgcn_rcpf(wp[c] + wext);
    zl[cp] = v;
    zp += v;
  }
  #pragma unroll
  for (int o = 32; o; o >>= 1) zp += __shfl_xor(zp, o);
  if (lane == 0) red[wid] = zp;
  __syncthreads();
  float Z = red[0] + red[1] + red[2] + red[3];

  int cb0 = lane * 16;
  float zv[48];
  #pragma unroll
  for (int s = 0; s < 3; s++){
    int cb = s*1024 + cb0;
    if (cb < ldc){
      #pragma unroll
      for (int q = 0; q < 4; q++){
        float4 t4 = *(const float4*)(zl + cb + q*4);
        zv[s*16+q*4+0]=t4.x; zv[s*16+q*4+1]=t4.y; zv[s*16+q*4+2]=t4.z; zv[s*16+q*4+3]=t4.w;
      }
    } else {
      #pragma unroll
      for (int k = 0; k < 16; k++) zv[s*16+k] = 0.f;
    }
  }

  int rpb = (nt + BPT - 1) / BPT;
  int r0 = b * rpb, r1 = min(r0 + rpb, nt);
  const u8* Kz = Kc + (size_t)z * CAPC;
  float wsum = 0.f;
  uint4 zq; zq.x=0u; zq.y=0u; zq.z=0u; zq.w=0u;

  int r = r0 + wid;
  uint4 cur[3] = {zq, zq, zq};
  if (r < r1){
    const u8* Kr = Kz + (size_t)r * ldc;
    cur[0] = *(const uint4*)(Kr + cb0);
    if (1024 + cb0 < ldc) cur[1] = *(const uint4*)(Kr + 1024 + cb0);
    if (2048 + cb0 < ldc) cur[2] = *(const uint4*)(Kr + 2048 + cb0);
  }
  while (r < r1){
    int rn = r + 4;
    uint4 nxt[3] = {zq, zq, zq};
    if (rn < r1){
      const u8* Krn = Kz + (size_t)rn * ldc;
      nxt[0] = *(const uint4*)(Krn + cb0);
      if (1024 + cb0 < ldc) nxt[1] = *(const uint4*)(Krn + 1024 + cb0);
      if (2048 + cb0 < ldc) nxt[2] = *(const uint4*)(Krn + 2048 + cb0);
    }
    float d4[4] = {0.f, 0.f, 0.f, 0.f};
    #pragma unroll
    for (int s = 0; s < 3; s++){
      float kd[16];
      dec16(cur[s], kd);
      #pragma unroll
      for (int k = 0; k < 16; k++){
        float c0 = kd[k];
        d4[k & 3] = fmaf((c0 + EPSK) * zv[s*16+k], __logf(fmaxf(c0, 1e-4f)), d4[k & 3]);
      }
    }
    float inner = (d4[0] + d4[1]) + (d4[2] + d4[3]);
    #pragma unroll
    for (int o = 32; o; o >>= 1) inner += __shfl_xor(inner, o);
    wsum += ubuf[(size_t)z * WSTR + r] * inner;
    cur[0] = nxt[0]; cur[1] = nxt[1]; cur[2] = nxt[2];
    r = rn;
  }
  if (lane == 0) unsafeAtomicAdd(tsacc + ts0 + z, -invlam * wsum);
  if (b == 0 && tid == 0){
    float aug = delta * kce * (UNT * Z + SU * znc);
    unsafeAtomicAdd(tsacc + ts0 + z, aug);
  }
}

// ---------------- out = 2 * sum_ts ----------------------------------------------------
__global__ void k_out(const float* __restrict__ tsacc, float* __restrict__ out)
{
  if (threadIdx.x == 0){
    float s = 0.f;
    for (int i = 0; i < SS; i++) s += tsacc[i];
    out[0] = 2.0f * s;
  }
}

extern "C" void kernel_launch(void* const* d_in, const int* in_sizes, int n_in,
                              void* d_out, int out_size, void* d_ws, size_t ws_size,
                              hipStream_t stream)
{
  const float* X = (const float*)d_in[0];
  const int* t = (const int*)d_in[1];

  const size_t PER_TS = 6810000u;
  const size_t FIXED  = 262144u;
  int TSG = 1;
  if (ws_size > FIXED + PER_TS){
    size_t g = (ws_size - FIXED) / PER_TS;
    TSG = (g > SS) ? SS : (int)g;
  }

  char* pp = (char*)d_ws;
  auto alloc = [&](size_t bytes) -> void* {
    void* r = (void*)pp;
    pp += (bytes + 255) & ~(size_t)255;
    return r;
  };
  u8*    Kbuf  = (u8*)alloc((size_t)TSG * CAPC);
  u16*   XT    = (u16*)alloc((size_t)TSG * NTOT * DD * 2);
  u16*   XC    = (u16*)alloc((size_t)TSG * NTOT * DD * 2);
  float* nxT   = (float*)alloc((size_t)TSG * NTOT * 4);
  float* nxC   = (float*)alloc((size_t)TSG * NTOT * 4);
  float* wbuf  = (float*)alloc((size_t)(NITER + 1) * TSG * WSTR * 4);
  float* ubuf  = (float*)alloc((size_t)TSG * WSTR * 4);
  float* auxf  = (float*)alloc((size_t)TSG * 272 * 4);
  int*   itidx = (int*)alloc(NTOT * 4);
  int*   icidx = (int*)alloc(NTOT * 4);
  int*   meta  = (int*)alloc(256);
  float* fmeta = (float*)alloc(256);
  float* tsacc = (float*)alloc(256);

  float* gsx   = auxf;
  float* gsn   = auxf + (size_t)TSG*256;
  float* stats = gsn + (size_t)TSG*2;
  const int auxn = TSG * 266;
  const int wn  = (NITER + 1) * TSG * WSTR;

  k_zero<<<1, 256, 0, stream>>>(tsacc, 64);
  k_compact<<<1, 1024, 0, stream>>>(t, itidx, icidx, meta, fmeta);

  for (int ts0 = 0; ts0 < SS; ts0 += TSG){
    int cnt = SS - ts0; if (cnt > TSG) cnt = TSG;

    k_zero<<<(auxn + 255)/256, 256, 0, stream>>>(auxf, auxn);
    k_zero<<<(wn + 255)/256, 256, 0, stream>>>(wbuf, wn);
    k_vinit<<<cnt, 64, 0, stream>>>(fmeta, wbuf);
    k_pack<<<dim3(16, 2, cnt), 256, 0, stream>>>(X, itidx, icidx, meta, XT, XC, nxT, nxC, ts0);
    k_stats<<<dim3(8, 2, cnt), 256, 0, stream>>>(XT, XC, nxT, nxC, meta, gsx, gsn);
    k_lam<<<cnt, 128, 0, stream>>>(gsx, gsn, meta, stats);
    k_gemm<<<dim3(18, 18, cnt), 256, 0, stream>>>(XT, XC, nxT, nxC, meta, fmeta, stats, Kbuf, wbuf);

    for (int it = 0; it < NITER; it++){
      k_iter<<<dim3(BPT, cnt), 256, 0, stream>>>(Kbuf,
          wbuf + (size_t)it * TSG * WSTR,
          wbuf + (size_t)(it + 1) * TSG * WSTR,
          ubuf, meta, fmeta, stats, (it == NITER - 1) ? 1 : 0);
    }
    k_fin<<<dim3(BPT, cnt), 256, 0, stream>>>(Kbuf,
        wbuf + (size_t)NITER * TSG * WSTR, ubuf, meta, fmeta, stats, tsacc, ts0);
  }
  k_out<<<1, 64, 0, stream>>>(tsacc, (float*)d_out);
}

// Round 6
// 1245.619 us; speedup vs baseline: 1.6397x; 1.6397x over previous
//
#include <hip/hip_runtime.h>
#include <stdint.h>

typedef unsigned char u8;
typedef unsigned short u16;
typedef uint32_t u32;

#define NTOT 4096
#define SS   32
#define DD   128
#define EPSK 1e-6f
#define NITER 20
#define CAPC 4460544u      // max nt*roundup(nc,128) over all splits with nt,nc<=2304
#define LDC_FIT 2304       // LDS-resident z/w limit (nt,nc=2048±8sigma safe)
#define WSTR 2432          // per-ts vector stride (floats)
#define SU_OFF 2308
#define UNT_OFF 2309
#define BPT 16             // blocks per ts in iteration kernels (16*32=512 = 2/CU)

typedef __attribute__((ext_vector_type(8))) short short8;
typedef __attribute__((ext_vector_type(4))) float f32x4;
typedef __attribute__((ext_vector_type(2))) float f32x2;

__device__ __forceinline__ float bf2f(u16 h){ return __uint_as_float(((u32)h) << 16); }
__device__ __forceinline__ u16 f2bf(float f){
  u32 u = __float_as_uint(f);
  u += 0x7fffu + ((u >> 16) & 1u);
  return (u16)(u >> 16);
}
// column permutation within each 64-col group: col j*16+r  <->  stored r*4+j
__device__ __forceinline__ int invpermc(int cp){
  return (cp & ~63) | ((cp & 3) << 4) | ((cp >> 2) & 15);
}

// ---------------- compact treated/control index lists --------------------------------
__global__ __launch_bounds__(1024) void k_compact(const int* __restrict__ t,
    int* __restrict__ itidx, int* __restrict__ icidx, int* __restrict__ meta,
    float* __restrict__ fmeta)
{
  __shared__ int sc[1024];
  int tid = threadIdx.x;
  int e0 = tid * 4;
  int tv[4]; int c = 0;
  #pragma unroll
  for (int e = 0; e < 4; e++){ tv[e] = t[e0 + e]; c += (tv[e] > 0) ? 1 : 0; }
  sc[tid] = c;
  __syncthreads();
  for (int off = 1; off < 1024; off <<= 1){
    int v = sc[tid];
    int add = (tid >= off) ? sc[tid - off] : 0;
    __syncthreads();
    sc[tid] = v + add;
    __syncthreads();
  }
  int incl = sc[tid];
  int excl = incl - c;
  int oT = excl, oC = e0 - excl;
  #pragma unroll
  for (int e = 0; e < 4; e++){
    if (tv[e] > 0) itidx[oT++] = e0 + e;
    else           icidx[oC++] = e0 + e;
  }
  if (tid == 1023){
    meta[0] = incl; meta[1] = NTOT - incl;
    fmeta[0] = (float)incl / (float)NTOT;
  }
}

__global__ void k_zero(float* __restrict__ p, int n)
{
  int i = blockIdx.x * 256 + threadIdx.x;
  if (i < n) p[i] = 0.f;
}

// ---------------- init w-slot-0 scalars -----------------------------------------------
__global__ void k_vinit(const float* __restrict__ fmeta, float* __restrict__ w0)
{
  if (threadIdx.x == 0){
    float p = fmeta[0];
    float* w = w0 + (size_t)blockIdx.x * WSTR;
    w[SU_OFF]  = p;
    w[UNT_OFF] = 1.0f - p;
  }
}

// ---------------- gather X -> bf16 Xt/Xc + row norms ----------------------------------
__global__ __launch_bounds__(256) void k_pack(const float* __restrict__ X,
    const int* __restrict__ itidx, const int* __restrict__ icidx,
    const int* __restrict__ meta, u16* __restrict__ XT, u16* __restrict__ XC,
    float* __restrict__ nxT, float* __restrict__ nxC, int ts0)
{
  int r = blockIdx.x * 256 + threadIdx.x;
  int isC = blockIdx.y;
  int z = blockIdx.z;
  int s = ts0 + z;
  int n = isC ? meta[1] : meta[0];
  if (r >= n) return;
  int idx = isC ? icidx[r] : itidx[r];
  const float4* src = (const float4*)(X + ((size_t)idx * SS + s) * DD);
  u16* dst = (isC ? XC : XT) + ((size_t)z * NTOT + r) * DD;
  float nrm = 0.f;
  #pragma unroll
  for (int q = 0; q < 32; q++){
    float4 v = src[q];
    nrm += v.x*v.x + v.y*v.y + v.z*v.z + v.w*v.w;
    u32 lo = (u32)f2bf(v.x) | ((u32)f2bf(v.y) << 16);
    u32 hi = (u32)f2bf(v.z) | ((u32)f2bf(v.w) << 16);
    uint2 pk; pk.x = lo; pk.y = hi;
    ((uint2*)dst)[q] = pk;
  }
  (isC ? nxC : nxT)[z * NTOT + r] = nrm;
}

// ---------------- per-ts column sums + norm sums (for analytic mean(M)) ---------------
__global__ __launch_bounds__(256) void k_stats(const u16* __restrict__ XT,
    const u16* __restrict__ XC, const float* __restrict__ nxT, const float* __restrict__ nxC,
    const int* __restrict__ meta, float* __restrict__ gsx, float* __restrict__ gsn)
{
  int side = blockIdx.y, z = blockIdx.z;
  int n = side ? meta[1] : meta[0];
  int chunk = (n + 7) >> 3;
  int r0 = blockIdx.x * chunk;
  int r1 = min(r0 + chunk, n);
  const u16* B = (side ? XC : XT) + (size_t)z * NTOT * DD;
  int tid = threadIdx.x;
  int d = tid & 127, half = tid >> 7;
  float sx = 0.f;
  for (int r = r0 + half; r < r1; r += 2) sx += bf2f(B[(size_t)r * DD + d]);
  __shared__ float sp[256];
  sp[tid] = sx;
  __syncthreads();
  if (tid < 128) unsafeAtomicAdd(&gsx[(size_t)(z*2+side)*128 + tid], sp[tid] + sp[tid+128]);
  const float* nrm = (side ? nxC : nxT) + (size_t)z * NTOT;
  float sn = 0.f;
  for (int r = r0 + tid; r < r1; r += 256) sn += nrm[r];
  #pragma unroll
  for (int o = 32; o; o >>= 1) sn += __shfl_xor(sn, o);
  __syncthreads();
  if ((tid & 63) == 0) sp[tid >> 6] = sn;
  __syncthreads();
  if (tid == 0) unsafeAtomicAdd(&gsn[z*2+side], sp[0]+sp[1]+sp[2]+sp[3]);
}

// ---------------- lam = nt*nc/sum(M) analytically --------------------------------------
__global__ void k_lam(const float* __restrict__ gsx, const float* __restrict__ gsn,
                      const int* __restrict__ meta, float* __restrict__ stats)
{
  int z = blockIdx.x, tid = threadIdx.x;  // 128 threads
  float d = gsx[(size_t)(z*2)*128 + tid] * gsx[(size_t)(z*2+1)*128 + tid];
  #pragma unroll
  for (int o = 32; o; o >>= 1) d += __shfl_xor(d, o);
  __shared__ float rr[2];
  if ((tid & 63) == 0) rr[tid >> 6] = d;
  __syncthreads();
  if (tid == 0){
    float nt = (float)meta[0], nc = (float)meta[1];
    float msum = nc * gsn[z*2] + nt * gsn[z*2+1] - 2.f * (rr[0] + rr[1]);
    stats[z*8+0] = nt * nc / msum;   // lam
    stats[z*8+1] = msum / (nt * nc); // 1/lam = mean(M)
  }
}

// ---------------- GEMM: K = fp8(exp(-lam*M)) (HW cvt, permuted direct store) ----------
// NOTE: no min-waves bound — __launch_bounds__(256,4) in R5 capped VGPR at 64 and
// spilled the 64-reg accumulator to scratch (WRITE_SIZE doubled). Default occupancy
// (VGPR ~116 + AGPR) is stall-prone but spill-free.
#define LDA2 72
__global__ __launch_bounds__(256) void k_gemm(const u16* __restrict__ XT,
    const u16* __restrict__ XC, const float* __restrict__ nxT, const float* __restrict__ nxC,
    const int* __restrict__ meta, const float* __restrict__ fmeta,
    float* __restrict__ stats, u8* __restrict__ Kc, float* __restrict__ w0base)
{
  int nt = meta[0], nc = meta[1];
  if (nt > LDC_FIT || nc > LDC_FIT) return;
  int bx = blockIdx.x, by = blockIdx.y, z = blockIdx.z;
  if (by * 128 >= nt || bx * 128 >= nc) return;
  __shared__ __align__(16) u16 As[128 * LDA2];
  __shared__ __align__(16) u16 Bs[128 * LDA2];
  __shared__ float watile[256];
  __shared__ float nxs[128];
  __shared__ float nys[128];
  int tid = threadIdx.x;
  int wid = tid >> 6, lane = tid & 63;
  int wm = (wid >> 1) * 64, wn = (wid & 1) * 64;
  int lrow = lane & 15, lquad = lane >> 4;

  // stage this block's row/col norms into LDS (coalesced, once)
  if (tid < 128){
    int gi = by*128 + tid;
    nxs[tid] = (gi < nt) ? nxT[(size_t)z * NTOT + gi] : 0.f;
  } else {
    int gj = bx*128 + (tid - 128);
    nys[tid - 128] = (gj < nc) ? nxC[(size_t)z * NTOT + gj] : 0.f;
  }

  f32x4 acc[4][4];
  #pragma unroll
  for (int i = 0; i < 4; i++){
    #pragma unroll
    for (int j = 0; j < 4; j++){
      acc[i][j][0]=0.f; acc[i][j][1]=0.f; acc[i][j][2]=0.f; acc[i][j][3]=0.f;
    }
  }

  int r = tid & 127;
  int isB = tid >> 7;
  int g = (isB ? bx : by) * 128 + r;
  int lim = isB ? nc : nt;
  const u16* srcbase = (isB ? XC : XT) + ((size_t)z * NTOT + g) * DD;
  u16* dl = (isB ? Bs : As) + r * LDA2;

  for (int kh = 0; kh < 2; kh++){
    __syncthreads();
    if (g < lim){
      const uint4* src = (const uint4*)(srcbase + kh * 64);
      #pragma unroll
      for (int q = 0; q < 8; q++) ((uint4*)dl)[q] = src[q];
    } else {
      uint4 zz; zz.x=0; zz.y=0; zz.z=0; zz.w=0;
      #pragma unroll
      for (int q = 0; q < 8; q++) ((uint4*)dl)[q] = zz;
    }
    __syncthreads();
    #pragma unroll
    for (int ks = 0; ks < 2; ks++){
      int koff = ks * 32 + lquad * 8;
      short8 af[4], bfr[4];
      #pragma unroll
      for (int i = 0; i < 4; i++) af[i]  = *(const short8*)(As + (wm + i*16 + lrow) * LDA2 + koff);
      #pragma unroll
      for (int j = 0; j < 4; j++) bfr[j] = *(const short8*)(Bs + (wn + j*16 + lrow) * LDA2 + koff);
      #pragma unroll
      for (int i = 0; i < 4; i++){
        #pragma unroll
        for (int j = 0; j < 4; j++){
          acc[i][j] = __builtin_amdgcn_mfma_f32_16x16x32_bf16(af[i], bfr[j], acc[i][j], 0, 0, 0);
        }
      }
    }
  }

  // ---- epilogue: exp -> HW fp8 pack -> permuted coalesced u32 stores ----
  int ldc = (nc + 127) & ~127;
  float lam = stats[z*8+0];
  float p = fmeta[0];
  float a0 = p / (float)nt;
  u8* Kz = Kc + (size_t)z * CAPC;

  float nyv[4]; bool jin[4];
  #pragma unroll
  for (int j = 0; j < 4; j++){
    int lcol = wn + j*16 + lrow;
    jin[j] = (bx*128 + lcol) < nc;
    nyv[j] = nys[lcol];
  }
  float vmax = 0.f;
  float colsum[4] = {0.f, 0.f, 0.f, 0.f};
  size_t cbase = (size_t)(bx*128 + wn + lrow*4);
  #pragma unroll
  for (int i = 0; i < 4; i++){
    #pragma unroll
    for (int rr2 = 0; rr2 < 4; rr2++){
      int lr = wm + i*16 + lquad*4 + rr2;
      int gi = by*128 + lr;
      bool iin = gi < nt;
      float nxv = nxs[lr];
      float cv[4];
      #pragma unroll
      for (int j = 0; j < 4; j++){
        float m = nxv + nyv[j] - 2.0f * acc[i][j][rr2];
        cv[j] = __expf(-lam * m);
        if (iin && jin[j]){ vmax = fmaxf(vmax, m); colsum[j] += cv[j]; }
      }
      u32 pk = (u32)__builtin_amdgcn_cvt_pk_fp8_f32(cv[0], cv[1], 0, false);
      pk = (u32)__builtin_amdgcn_cvt_pk_fp8_f32(cv[2], cv[3], (int)pk, true);
      if (iin) *(u32*)(Kz + (size_t)gi * ldc + cbase) = pk;
    }
  }
  // merge colsum over the 4 quads of this wave
  #pragma unroll
  for (int j = 0; j < 4; j++){
    colsum[j] += __shfl_xor(colsum[j], 16);
    colsum[j] += __shfl_xor(colsum[j], 32);
  }
  if (lane < 16){
    #pragma unroll
    for (int j = 0; j < 4; j++) watile[wid * 64 + j*16 + lrow] = colsum[j];
  }
  #pragma unroll
  for (int o = 32; o; o >>= 1) vmax = fmaxf(vmax, __shfl_xor(vmax, o));
  if (lane == 0) atomicMax((int*)stats + z*8 + 2, __float_as_int(vmax));
  __syncthreads();
  // w0 = (p/nt) * column sums
  if (tid < 128){
    int gj = bx*128 + tid;
    if (gj < nc){
      float v = (tid < 64) ? (watile[tid] + watile[128 + tid])
                           : (watile[64 + (tid-64)] + watile[192 + (tid-64)]);
      unsafeAtomicAdd(w0base + (size_t)z * WSTR + gj, v * a0);
    }
  }
}

// ---------------- fused Sinkhorn iteration: z(w) -> u' -> w' = K^T u' ------------------
// R4 structure (private per-wave watw stripes + single decode) — R5's LDS-atomic
// flush and double-decode regressed it 2x.
__global__ __launch_bounds__(256, 2) void k_iter(const u8* __restrict__ Kc,
    const float* __restrict__ wprev, float* __restrict__ wnext,
    float* __restrict__ ubuf, const int* __restrict__ meta,
    const float* __restrict__ fmeta, const float* __restrict__ stats, int writeU)
{
  __shared__ __align__(16) float zl[LDC_FIT];
  __shared__ __align__(16) float watw[4 * LDC_FIT];
  __shared__ float red[4];
  int nt = meta[0], nc = meta[1];
  if (nt > LDC_FIT || nc > LDC_FIT) return;
  int ldc = (nc + 127) & ~127;
  int z = blockIdx.y, b = blockIdx.x;
  int tid = threadIdx.x, wid = tid >> 6, lane = tid & 63;
  float p = fmeta[0];
  float b0 = (1.0f - p) / (float)nc;
  float a0 = p / (float)nt;
  float lam = stats[z*8+0];
  float delta = stats[z*8+2];
  float kc = __expf(-lam * delta);
  float kce = kc + EPSK;
  const float* wp = wprev + (size_t)z * WSTR;
  float* wnx = wnext + (size_t)z * WSTR;
  float SU = wp[SU_OFF], UNT = wp[UNT_OFF];
  float wext = EPSK * (SU + UNT) + kc * UNT;
  float wnc = kce * SU + (1.0f + EPSK) * UNT;
  float znc = p / wnc;

  // stage z into LDS in PERMUTED order
  float zp = 0.f;
  for (int cp = tid; cp < ldc; cp += 256){
    int c = invpermc(cp);
    float v = 0.f;
    if (c < nc) v = b0 * __builtin_amdgcn_rcpf(wp[c] + wext);
    zl[cp] = v;
    zp += v;
  }
  #pragma unroll
  for (int o = 32; o; o >>= 1) zp += __shfl_xor(zp, o);
  if (lane == 0) red[wid] = zp;
  __syncthreads();
  float Z = red[0] + red[1] + red[2] + red[3];
  float dotX = EPSK * Z + kce * znc;
  float untN = (1.0f - p) / (kce * Z + (1.0f + EPSK) * znc);

  // hoist this lane's 48 z values into registers (hot loop: no LDS)
  int cb0 = lane * 16;
  float zv[48];
  #pragma unroll
  for (int s = 0; s < 3; s++){
    int cb = s*1024 + cb0;
    if (cb < ldc){
      #pragma unroll
      for (int q = 0; q < 4; q++){
        float4 t4 = *(const float4*)(zl + cb + q*4);
        zv[s*16+q*4+0]=t4.x; zv[s*16+q*4+1]=t4.y; zv[s*16+q*4+2]=t4.z; zv[s*16+q*4+3]=t4.w;
      }
    } else {
      #pragma unroll
      for (int k = 0; k < 16; k++) zv[s*16+k] = 0.f;
    }
  }

  float wacc[48];
  #pragma unroll
  for (int k = 0; k < 48; k++) wacc[k] = 0.f;
  float rsum = 0.f;

  int rpb = (nt + BPT - 1) / BPT;
  int r0 = b * rpb, r1 = min(r0 + rpb, nt);
  const u8* Kz = Kc + (size_t)z * CAPC;

  for (int r = r0 + wid; r < r1; r += 4){
    const u8* Kr = Kz + (size_t)r * ldc;
    uint4 kq[3];
    #pragma unroll
    for (int s = 0; s < 3; s++){
      int cb = s*1024 + cb0;
      if (cb < ldc) kq[s] = *(const uint4*)(Kr + cb);
      else { kq[s].x=0u; kq[s].y=0u; kq[s].z=0u; kq[s].w=0u; }
    }
    float kd[48];
    #pragma unroll
    for (int s = 0; s < 3; s++){
      u32 wd[4] = {kq[s].x, kq[s].y, kq[s].z, kq[s].w};
      #pragma unroll
      for (int q = 0; q < 4; q++){
        f32x2 d0 = __builtin_amdgcn_cvt_pk_f32_fp8((int)wd[q], false);
        f32x2 d1 = __builtin_amdgcn_cvt_pk_f32_fp8((int)wd[q], true);
        kd[s*16+q*4+0] = d0.x; kd[s*16+q*4+1] = d0.y;
        kd[s*16+q*4+2] = d1.x; kd[s*16+q*4+3] = d1.y;
      }
    }
    float d4[4] = {0.f, 0.f, 0.f, 0.f};
    #pragma unroll
    for (int k = 0; k < 48; k++) d4[k & 3] = fmaf(kd[k], zv[k], d4[k & 3]);
    float dot = (d4[0] + d4[1]) + (d4[2] + d4[3]);
    #pragma unroll
    for (int o = 32; o; o >>= 1) dot += __shfl_xor(dot, o);
    float uv = a0 * __builtin_amdgcn_rcpf(dot + dotX);
    rsum += uv;
    if (writeU && lane == 0) ubuf[(size_t)z * WSTR + r] = uv;
    #pragma unroll
    for (int k = 0; k < 48; k++) wacc[k] = fmaf(kd[k], uv, wacc[k]);
  }
  // per-wave private LDS copy, then merged global atomic (unpermute here)
  #pragma unroll
  for (int s = 0; s < 3; s++){
    int cb = s*1024 + cb0;
    if (cb < ldc){
      #pragma unroll
      for (int q = 0; q < 4; q++)
        *(float4*)(watw + (size_t)wid * LDC_FIT + cb + q*4) =
            make_float4(wacc[s*16+q*4+0], wacc[s*16+q*4+1], wacc[s*16+q*4+2], wacc[s*16+q*4+3]);
    }
  }
  if (lane == 0) unsafeAtomicAdd(wnx + SU_OFF, rsum);
  if (b == 0 && tid == 0) wnx[UNT_OFF] = untN;
  __syncthreads();
  for (int cp = tid; cp < ldc; cp += 256){
    int c = invpermc(cp);
    if (c < nc){
      float v = watw[cp] + watw[LDC_FIT + cp] + watw[2*LDC_FIT + cp] + watw[3*LDC_FIT + cp];
      unsafeAtomicAdd(wnx + c, v);
    }
  }
}

// ---------------- final: tsacc += sum(T * Mt), M recovered via -log(K)/lam -------------
__global__ __launch_bounds__(256, 2) void k_fin(const u8* __restrict__ Kc,
    const float* __restrict__ wprev, const float* __restrict__ ubuf,
    const int* __restrict__ meta, const float* __restrict__ fmeta,
    const float* __restrict__ stats, float* __restrict__ tsacc, int ts0)
{
  __shared__ __align__(16) float zl[LDC_FIT];
  __shared__ float red[4];
  int nt = meta[0], nc = meta[1];
  if (nt > LDC_FIT || nc > LDC_FIT) return;
  int ldc = (nc + 127) & ~127;
  int z = blockIdx.y, b = blockIdx.x;
  int tid = threadIdx.x, wid = tid >> 6, lane = tid & 63;
  float p = fmeta[0];
  float b0 = (1.0f - p) / (float)nc;
  float lam = stats[z*8+0];
  float invlam = stats[z*8+1];
  float delta = stats[z*8+2];
  float kc = __expf(-lam * delta);
  float kce = kc + EPSK;
  const float* wp = wprev + (size_t)z * WSTR;
  float SU = wp[SU_OFF], UNT = wp[UNT_OFF];
  float wext = EPSK * (SU + UNT) + kc * UNT;
  float wnc = kce * SU + (1.0f + EPSK) * UNT;
  float znc = p / wnc;

  float zp = 0.f;
  for (int cp = tid; cp < ldc; cp += 256){
    int c = invpermc(cp);
    float v = 0.f;
    if (c < nc) v = b0 * __builtin_amdgcn_rcpf(wp[c] + wext);
    zl[cp] = v;
    zp += v;
  }
  #pragma unroll
  for (int o = 32; o; o >>= 1) zp += __shfl_xor(zp, o);
  if (lane == 0) red[wid] = zp;
  __syncthreads();
  float Z = red[0] + red[1] + red[2] + red[3];

  int cb0 = lane * 16;
  float zv[48];
  #pragma unroll
  for (int s = 0; s < 3; s++){
    int cb = s*1024 + cb0;
    if (cb < ldc){
      #pragma unroll
      for (int q = 0; q < 4; q++){
        float4 t4 = *(const float4*)(zl + cb + q*4);
        zv[s*16+q*4+0]=t4.x; zv[s*16+q*4+1]=t4.y; zv[s*16+q*4+2]=t4.z; zv[s*16+q*4+3]=t4.w;
      }
    } else {
      #pragma unroll
      for (int k = 0; k < 16; k++) zv[s*16+k] = 0.f;
    }
  }

  int rpb = (nt + BPT - 1) / BPT;
  int r0 = b * rpb, r1 = min(r0 + rpb, nt);
  const u8* Kz = Kc + (size_t)z * CAPC;
  float wsum = 0.f;

  for (int r = r0 + wid; r < r1; r += 4){
    const u8* Kr = Kz + (size_t)r * ldc;
    float d4[4] = {0.f, 0.f, 0.f, 0.f};
    #pragma unroll
    for (int s = 0; s < 3; s++){
      int cb = s*1024 + cb0;
      if (cb < ldc){
        uint4 kq = *(const uint4*)(Kr + cb);
        u32 wd[4] = {kq.x, kq.y, kq.z, kq.w};
        #pragma unroll
        for (int q = 0; q < 4; q++){
          f32x2 d0 = __builtin_amdgcn_cvt_pk_f32_fp8((int)wd[q], false);
          f32x2 d1 = __builtin_amdgcn_cvt_pk_f32_fp8((int)wd[q], true);
          float cc[4] = {d0.x, d0.y, d1.x, d1.y};
          int k0 = s*16+q*4;
          #pragma unroll
          for (int e = 0; e < 4; e++){
            d4[e] = fmaf((cc[e] + EPSK) * zv[k0+e], __logf(fmaxf(cc[e], 1e-4f)), d4[e]);
          }
        }
      }
    }
    float inner = (d4[0] + d4[1]) + (d4[2] + d4[3]);
    #pragma unroll
    for (int o = 32; o; o >>= 1) inner += __shfl_xor(inner, o);
    wsum += ubuf[(size_t)z * WSTR + r] * inner;
  }
  if (lane == 0) unsafeAtomicAdd(tsacc + ts0 + z, -invlam * wsum);
  if (b == 0 && tid == 0){
    float aug = delta * kce * (UNT * Z + SU * znc);
    unsafeAtomicAdd(tsacc + ts0 + z, aug);
  }
}

// ---------------- out = 2 * sum_ts ----------------------------------------------------
__global__ void k_out(const float* __restrict__ tsacc, float* __restrict__ out)
{
  if (threadIdx.x == 0){
    float s = 0.f;
    for (int i = 0; i < SS; i++) s += tsacc[i];
    out[0] = 2.0f * s;
  }
}

extern "C" void kernel_launch(void* const* d_in, const int* in_sizes, int n_in,
                              void* d_out, int out_size, void* d_ws, size_t ws_size,
                              hipStream_t stream)
{
  const float* X = (const float*)d_in[0];
  const int* t = (const int*)d_in[1];

  // TSG cap raised to 32: full-problem single group (K = 143 MB, L3-resident),
  // halves iter dispatch count and doubles per-launch parallelism.
  const size_t PER_TS = 6810000u;
  const size_t FIXED  = 262144u;
  int TSG = 1;
  if (ws_size > FIXED + PER_TS){
    size_t g = (ws_size - FIXED) / PER_TS;
    TSG = (g > SS) ? SS : (int)g;
  }

  char* pp = (char*)d_ws;
  auto alloc = [&](size_t bytes) -> void* {
    void* r = (void*)pp;
    pp += (bytes + 255) & ~(size_t)255;
    return r;
  };
  u8*    Kbuf  = (u8*)alloc((size_t)TSG * CAPC);
  u16*   XT    = (u16*)alloc((size_t)TSG * NTOT * DD * 2);
  u16*   XC    = (u16*)alloc((size_t)TSG * NTOT * DD * 2);
  float* nxT   = (float*)alloc((size_t)TSG * NTOT * 4);
  float* nxC   = (float*)alloc((size_t)TSG * NTOT * 4);
  float* wbuf  = (float*)alloc((size_t)(NITER + 1) * TSG * WSTR * 4);
  float* ubuf  = (float*)alloc((size_t)TSG * WSTR * 4);
  float* auxf  = (float*)alloc((size_t)TSG * 272 * 4);
  int*   itidx = (int*)alloc(NTOT * 4);
  int*   icidx = (int*)alloc(NTOT * 4);
  int*   meta  = (int*)alloc(256);
  float* fmeta = (float*)alloc(256);
  float* tsacc = (float*)alloc(256);

  float* gsx   = auxf;
  float* gsn   = auxf + (size_t)TSG*256;
  float* stats = gsn + (size_t)TSG*2;
  const int auxn = TSG * 266;
  const int wn  = (NITER + 1) * TSG * WSTR;

  k_zero<<<1, 256, 0, stream>>>(tsacc, 64);
  k_compact<<<1, 1024, 0, stream>>>(t, itidx, icidx, meta, fmeta);

  for (int ts0 = 0; ts0 < SS; ts0 += TSG){
    int cnt = SS - ts0; if (cnt > TSG) cnt = TSG;

    k_zero<<<(auxn + 255)/256, 256, 0, stream>>>(auxf, auxn);
    k_zero<<<(wn + 255)/256, 256, 0, stream>>>(wbuf, wn);
    k_vinit<<<cnt, 64, 0, stream>>>(fmeta, wbuf);
    k_pack<<<dim3(16, 2, cnt), 256, 0, stream>>>(X, itidx, icidx, meta, XT, XC, nxT, nxC, ts0);
    k_stats<<<dim3(8, 2, cnt), 256, 0, stream>>>(XT, XC, nxT, nxC, meta, gsx, gsn);
    k_lam<<<cnt, 128, 0, stream>>>(gsx, gsn, meta, stats);
    k_gemm<<<dim3(18, 18, cnt), 256, 0, stream>>>(XT, XC, nxT, nxC, meta, fmeta, stats, Kbuf, wbuf);

    for (int it = 0; it < NITER; it++){
      k_iter<<<dim3(BPT, cnt), 256, 0, stream>>>(Kbuf,
          wbuf + (size_t)it * TSG * WSTR,
          wbuf + (size_t)(it + 1) * TSG * WSTR,
          ubuf, meta, fmeta, stats, (it == NITER - 1) ? 1 : 0);
    }
    k_fin<<<dim3(BPT, cnt), 256, 0, stream>>>(Kbuf,
        wbuf + (size_t)NITER * TSG * WSTR, ubuf, meta, fmeta, stats, tsacc, ts0);
  }
  k_out<<<1, 64, 0, stream>>>(tsacc, (float*)d_out);
}